// Round 15
// baseline (1560.357 us; speedup 1.0000x reference)
//
#include <hip/hip_runtime.h>

// RGCN 2-layer graph encoder — R15: R13 base + LDS-free k_msg (occupancy).
//  * k_msg no longer stages W in LDS: B fragments read directly from Wf
//    (bucket-sequential blocks -> co-resident blocks share one rel's 32KB W
//    working set -> L1-resident). LDS 32KB->0 lifts the 16-waves/CU cap to 32.
//    launch_bounds(256, 8).
//  * everything else byte-identical to R13 (nt pm stores/loads, invc_t,
//    nch-adaptive chunking).

#define N_NODES 50000
#define N_EDGES 1200000
#define N_REL   40
#define N_BASES 30
#define EMB     64
#define HID     128
#define N_GRAPHS 64

#define NKEYC_MAX 160                                   // up to 4 chunks * 40 rels
#define PERM_CAP  ((size_t)N_EDGES + (size_t)NKEYC_MAX * 256)
#define SP_EPB    1024

typedef float f32x4  __attribute__((ext_vector_type(4)));
typedef short bf16x8 __attribute__((ext_vector_type(8)));

__device__ __forceinline__ unsigned short f2bf(float x) {
    unsigned int u = __float_as_uint(x);
    u = (u + 0x7FFFu + ((u >> 16) & 1u)) >> 16;   // RNE
    return (unsigned short)u;
}
__device__ __forceinline__ float bflo(unsigned int u) { return __uint_as_float(u << 16); }
__device__ __forceinline__ float bfhi(unsigned int u) { return __uint_as_float(u & 0xffff0000u); }

// ---------------- workspace layout (float units) ---------------- (R13 layout)
#define OFF_WF1   ((size_t)0)                    // 163,840
#define OFF_WF2   ((size_t)163840)               // 327,680
#define OFF_CNT   ((size_t)491520)               // 2,000,000 (cnt_t[r][n] -> inv)
#define OFF_H1    ((size_t)2491520)              // 6,400,000
#define OFF_H2    ((size_t)8891520)              // 6,400,000
#define OFF_HB1   ((size_t)15291520)             // 1,600,000
#define OFF_HB2   ((size_t)16891520)             // 3,200,000
#define OFF_CNTG  ((size_t)20091520)             // 64
#define OFF_POOL  ((size_t)20091584)             // 8,192
#define OFF_PSRC  ((size_t)20099776)             // 1,240,960
#define OFF_POS   ((size_t)21340736)             // 1,240,960
#define OFF_PDST  ((size_t)22581696)             // 1,240,960
#define OFF_HCR   ((size_t)23822656)             // 160
#define OFF_CCR   ((size_t)23822816)             // 160
#define OFF_POCR  ((size_t)23822976)             // 192 (161 used)
#define OFF_HD    ((size_t)23823168)             // 50,000
#define OFF_CD    ((size_t)23873168)             // 50,000
#define OFF_POD   ((size_t)23923168)             // 50,016
#define OFF_RF1   ((size_t)23973184)             // 4,096
#define OFF_RF2   ((size_t)23977280)             // 8,192
#define OFF_PM    ((size_t)23985472)             // capr(nch)*64 u32

// ---- W fragment generator (16x16x32 layout):
// Wf[r][((ct*KT+kt)*64+lane)*8+j] = W_r[kt*32+(lane>>4)*8+j][ct*16+(lane&15)]
template <int IN, int KT>
__global__ void k_Wfrag(const float* __restrict__ comp, const float* __restrict__ basis,
                        unsigned short* __restrict__ Wf) {
    const int FR = IN * HID;
    int idx = blockIdx.x * blockDim.x + threadIdx.x;
    if (idx >= N_REL * FR) return;
    int r = idx / FR, F = idx - r * FR;
    int j = F & 7, lane = (F >> 3) & 63, tt = F >> 9;
    int kt = tt % KT, ct = tt / KT;
    int k = kt * 32 + (lane >> 4) * 8 + j;
    int c = ct * 16 + (lane & 15);
    float s = 0.f;
#pragma unroll
    for (int b = 0; b < N_BASES; ++b)
        s += comp[r * N_BASES + b] * basis[((size_t)b * IN + k) * HID + c];
    Wf[idx] = f2bf(s);
}

template <int IN, int KT>
__global__ void k_rootfrag(const float* __restrict__ root, unsigned short* __restrict__ rf) {
    int idx = blockIdx.x * blockDim.x + threadIdx.x;
    if (idx >= IN * HID) return;
    int j = idx & 7, lane = (idx >> 3) & 63, tt = idx >> 9;
    int kt = tt % KT, ct = tt / KT;
    int k = kt * 32 + (lane >> 4) * 8 + j;
    int c = ct * 16 + (lane & 15);
    rf[idx] = f2bf(root[k * HID + c]);
}

// transposed count: cnt_t[r*N + d]
__global__ void k_count(const int* __restrict__ dst, const int* __restrict__ etype,
                        float* __restrict__ cnt_t) {
    int e = blockIdx.x * blockDim.x + threadIdx.x;
    if (e >= N_EDGES) return;
    atomicAdd(&cnt_t[(size_t)etype[e] * N_NODES + dst[e]], 1.0f);
}

// degree per node + IN-PLACE cnt_t -> 1/max(cnt,1)
__global__ void k_deg_inv(float* __restrict__ cnt_t, int* __restrict__ hist) {
    int n = blockIdx.x * blockDim.x + threadIdx.x;
    if (n >= N_NODES) return;
    float s = 0.f;
#pragma unroll 8
    for (int r = 0; r < N_REL; ++r) {
        float c = cnt_t[(size_t)r * N_NODES + n];
        s += c;
        cnt_t[(size_t)r * N_NODES + n] = 1.0f / fmaxf(c, 1.0f);
    }
    hist[n] = (int)(s + 0.5f);
}

// exclusive scan over N_NODES entries, po_d[N]=E
__global__ void k_scan_d(const int* __restrict__ hist, int* __restrict__ po) {
    __shared__ int csum[256];
    int t = threadIdx.x;
    const int CH = (N_NODES + 255) / 256;
    int k0 = t * CH, k1 = min(k0 + CH, N_NODES);
    int s = 0;
    for (int k = k0; k < k1; ++k) s += hist[k];
    csum[t] = s;
    __syncthreads();
    if (t == 0) {
        int acc = 0;
        for (int i = 0; i < 256; ++i) { int v = csum[i]; csum[i] = acc; acc += v; }
        po[N_NODES] = acc;
    }
    __syncthreads();
    int base = csum[t];
    for (int k = k0; k < k1; ++k) { po[k] = base; base += hist[k]; }
}

// (chunk, rel) histogram with LDS aggregation
__global__ void k_hist_cr(const int* __restrict__ dst, const int* __restrict__ etype,
                          int* __restrict__ hist, int chn, int nkeyc) {
    __shared__ int lh[NKEYC_MAX];
    int t = threadIdx.x;
    if (t < nkeyc) lh[t] = 0;
    __syncthreads();
    int e = blockIdx.x * blockDim.x + t;
    if (e < N_EDGES) atomicAdd(&lh[(dst[e] / chn) * N_REL + etype[e]], 1);
    __syncthreads();
    if (t < nkeyc && lh[t]) atomicAdd(&hist[t], lh[t]);
}

// scan nkeyc buckets, each padded to a multiple of 256
__global__ void k_scan_cr(const int* __restrict__ hist, int* __restrict__ po, int nkeyc) {
    if (threadIdx.x == 0) {
        int acc = 0;
        for (int k = 0; k < nkeyc; ++k) {
            po[k] = acc;
            acc += ((hist[k] + 255) >> 8) << 8;
        }
        po[nkeyc] = acc;
    }
}

// init streams: pads -> dump row
__global__ void k_fill(int* __restrict__ ps_src, int* __restrict__ ps_os,
                       int* __restrict__ ps_dst, int dumprow) {
    for (size_t s = (size_t)blockIdx.x * blockDim.x + threadIdx.x; s < PERM_CAP;
         s += (size_t)gridDim.x * blockDim.x) {
        ps_src[s] = 0;
        ps_os[s] = dumprow;
        ps_dst[s] = 0;
    }
}

// block-aggregated scatter into (chunk,rel)-major slots + dst-major oslot
__global__ void k_scatter_s(const int* __restrict__ src, const int* __restrict__ dst,
                            const int* __restrict__ etype,
                            const int* __restrict__ po_cr, int* __restrict__ cur_cr,
                            const int* __restrict__ po_d, int* __restrict__ cur_d,
                            int* __restrict__ ps_src, int* __restrict__ ps_os,
                            int* __restrict__ ps_dst, int chn, int nkeyc) {
    __shared__ int lh[NKEYC_MAX], sbase[NKEYC_MAX];
    int t = threadIdx.x;  // 256
    if (t < nkeyc) lh[t] = 0;
    __syncthreads();
    int e0 = blockIdx.x * SP_EPB;
    int e_[4], key_[4];
#pragma unroll
    for (int i = 0; i < 4; ++i) {
        int e = e0 + t + i * 256;
        e_[i] = e;
        if (e < N_EDGES) {
            key_[i] = (dst[e] / chn) * N_REL + etype[e];
            atomicAdd(&lh[key_[i]], 1);
        }
    }
    __syncthreads();
    if (t < nkeyc) { if (lh[t]) sbase[t] = atomicAdd(&cur_cr[t], lh[t]); lh[t] = 0; }
    __syncthreads();
#pragma unroll
    for (int i = 0; i < 4; ++i) {
        if (e_[i] < N_EDGES) {
            int e = e_[i], key = key_[i];
            int d = dst[e];
            int p = atomicAdd(&lh[key], 1);
            int slot = po_cr[key] + sbase[key] + p;
            int os_g = po_d[d] + atomicAdd(&cur_d[d], 1);
            int os_l = os_g - po_d[(d / chn) * chn];   // chunk-local pm row
            ps_src[slot] = src[e];
            ps_os[slot] = os_l;
            ps_dst[slot] = d;
        }
    }
}

// ---- MFMA root GEMM: h[n] = bias + hb[n] @ root ----
template <int IN, int KT>
__global__ __launch_bounds__(256, 4)
void k_rootgemm(const unsigned short* __restrict__ hb_in,
                const unsigned short* __restrict__ rf,
                const float* __restrict__ bias, float* __restrict__ h) {
    __shared__ unsigned short Wl[8 * KT * 64 * 8];
    {
        const f32x4* Wg = (const f32x4*)rf;
        f32x4* Wd = (f32x4*)Wl;
        for (int kk = threadIdx.x; kk < 8 * KT * 64; kk += 256) Wd[kk] = Wg[kk];
    }
    __syncthreads();

    int l = threadIdx.x & 63, wv = threadIdx.x >> 6;
    int lrow = l & 15, lk = l >> 4;
    int nbase = blockIdx.x * 64 + wv * 16;

    int nrow = min(nbase + lrow, N_NODES - 1);
    bf16x8 a[KT];
    const unsigned short* hrow = hb_in + (size_t)nrow * IN + lk * 8;
#pragma unroll
    for (int kt = 0; kt < KT; ++kt)
        a[kt] = *(const bf16x8*)(hrow + kt * 32);

    f32x4 acc[8];
#pragma unroll
    for (int ct = 0; ct < 8; ++ct) acc[ct] = (f32x4){0.f, 0.f, 0.f, 0.f};
#pragma unroll
    for (int ct = 0; ct < 8; ++ct) {
#pragma unroll
        for (int kt = 0; kt < KT; ++kt) {
            bf16x8 bb = *(const bf16x8*)(Wl + ((ct * KT + kt) * 64 + l) * 8);
            acc[ct] = __builtin_amdgcn_mfma_f32_16x16x32_bf16(a[kt], bb, acc[ct], 0, 0, 0);
        }
    }
#pragma unroll
    for (int q = 0; q < 4; ++q) {
        int n = nbase + lk * 4 + q;
        if (n < N_NODES) {
#pragma unroll
            for (int ct = 0; ct < 8; ++ct)
                h[(size_t)n * HID + ct * 16 + lrow] = acc[ct][q] + bias[ct * 16 + lrow];
        }
    }
}

// ---- Phase A: rel-major MFMA message kernel, LDS-FREE ----
// B fragments read directly from Wf (L1-resident: co-resident blocks are
// bucket-sequential, mostly same rel). No LDS -> up to 32 waves/CU.
template <int IN, int KT>
__global__ __launch_bounds__(256, 8)
void k_msg(const unsigned short* __restrict__ hb_in, const int* __restrict__ ps_src,
           const int* __restrict__ ps_os, const int* __restrict__ ps_dst,
           const float* __restrict__ invc_t,
           const int* __restrict__ po_cr,   // 41 entries for this chunk
           const unsigned short* __restrict__ Wf, unsigned int* __restrict__ pm) {
    int slot0 = po_cr[0] + blockIdx.x * 256;
    if (slot0 >= po_cr[N_REL]) return;
    int r = 0;
    while (po_cr[r + 1] <= slot0) ++r;

    const unsigned short* Wr = Wf + (size_t)r * (8 * KT * 64 * 8);

    int l = threadIdx.x & 63, wv = threadIdx.x >> 6;
    int lrow = l & 15, lk = l >> 4;
    const float* invr = invc_t + (size_t)r * N_NODES;

    for (int t = wv; t < 16; t += 4) {
        int slot = slot0 + t * 16 + lrow;
        int sv = ps_src[slot];
        int os = ps_os[slot];
        int d  = ps_dst[slot];
        float inv = invr[d];

        bf16x8 a[KT];
        const unsigned short* hrow = hb_in + (size_t)sv * IN + lk * 8;
#pragma unroll
        for (int kt = 0; kt < KT; ++kt)
            a[kt] = *(const bf16x8*)(hrow + kt * 32);

        f32x4 acc[8];
#pragma unroll
        for (int ct = 0; ct < 8; ++ct) acc[ct] = (f32x4){0.f, 0.f, 0.f, 0.f};
#pragma unroll
        for (int ct = 0; ct < 8; ++ct) {
#pragma unroll
            for (int kt = 0; kt < KT; ++kt) {
                bf16x8 bb = *(const bf16x8*)(Wr + ((size_t)(ct * KT + kt) * 64 + l) * 8);
                acc[ct] = __builtin_amdgcn_mfma_f32_16x16x32_bf16(a[kt], bb, acc[ct], 0, 0, 0);
            }
        }
        // scaled bf16-pack NONTEMPORAL store (pm written once, read once)
#pragma unroll
        for (int q = 0; q < 4; ++q) {
            int row = lk * 4 + q;
            int osq   = __shfl(os, row);
            float ivq = __shfl(inv, row);
            unsigned int* dp = pm + (size_t)osq * 64 + lrow;
#pragma unroll
            for (int cp = 0; cp < 4; ++cp) {
                unsigned int u = (unsigned int)f2bf(acc[2 * cp][q] * ivq)
                               | ((unsigned int)f2bf(acc[2 * cp + 1][q] * ivq) << 16);
                __builtin_nontemporal_store(u, dp + cp * 16);
            }
        }
    }
}

// ---- Phase B: dst-major streaming reduce (nontemporal pm loads) ----
template <bool WRITE_HB>
__global__ __launch_bounds__(256, 8)
void k_reduce(const unsigned int* __restrict__ pm, const int* __restrict__ po_d,
              int n0chunk, int chn, float* __restrict__ h,
              unsigned short* __restrict__ hb_out) {
    int wv = threadIdx.x >> 6, p = threadIdx.x & 63;
    int n = n0chunk + blockIdx.x * 4 + wv;
    if (n >= n0chunk + chn) return;
    int pmbase = po_d[n0chunk];
    int b0 = po_d[n] - pmbase;
    int cn = po_d[n + 1] - pmbase - b0;
    float lo = 0.f, hi = 0.f;
    const unsigned int* rp = pm + (size_t)b0 * 64 + p;
    int k = 0;
    for (; k + 4 <= cn; k += 4) {
        unsigned int u0 = __builtin_nontemporal_load(rp);
        unsigned int u1 = __builtin_nontemporal_load(rp + 64);
        unsigned int u2 = __builtin_nontemporal_load(rp + 128);
        unsigned int u3 = __builtin_nontemporal_load(rp + 192);
        rp += 256;
        lo += bflo(u0) + bflo(u1) + bflo(u2) + bflo(u3);
        hi += bfhi(u0) + bfhi(u1) + bfhi(u2) + bfhi(u3);
    }
    for (; k < cn; ++k) {
        unsigned int u = __builtin_nontemporal_load(rp);
        rp += 64;
        lo += bflo(u); hi += bfhi(u);
    }
    int cA = (p & 15) + 32 * (p >> 4);
    float* hp = h + (size_t)n * HID;
    float vA = fmaxf(hp[cA] + lo, 0.f);
    float vB = fmaxf(hp[cA + 16] + hi, 0.f);
    hp[cA] = vA;
    hp[cA + 16] = vB;
    if (WRITE_HB) {
        hb_out[(size_t)n * HID + cA] = f2bf(vA);
        hb_out[(size_t)n * HID + cA + 16] = f2bf(vB);
    }
}

// layer-1 A source: hb1[n][:] = bf16(node_emb[x[n]][:])
__global__ void k_cvt_emb(const float* __restrict__ emb, const int* __restrict__ x,
                          unsigned short* __restrict__ hb) {
    int idx = blockIdx.x * blockDim.x + threadIdx.x;
    if (idx >= N_NODES * (EMB / 4)) return;
    int n = idx / (EMB / 4), c4 = idx % (EMB / 4);
    int row = x[n];
    float4 v = *(const float4*)(emb + (size_t)row * EMB + c4 * 4);
    ushort4 o = {f2bf(v.x), f2bf(v.y), f2bf(v.z), f2bf(v.w)};
    *(ushort4*)(hb + (size_t)n * EMB + c4 * 4) = o;
}

__global__ void k_gcount2(const int* __restrict__ batch, float* __restrict__ cntG) {
    int g = threadIdx.x;
    if (g >= N_GRAPHS) return;
    int lo = 0, hi = N_NODES;
    while (lo < hi) { int m = (lo + hi) >> 1; if (batch[m] < g) lo = m + 1; else hi = m; }
    int lb0 = lo;
    lo = 0; hi = N_NODES;
    while (lo < hi) { int m = (lo + hi) >> 1; if (batch[m] < g + 1) lo = m + 1; else hi = m; }
    cntG[g] = (float)(lo - lb0);
}

__global__ void k_pool(const float* __restrict__ h, const int* __restrict__ batch,
                       float* __restrict__ acc) {
    const int CH = 64;
    int n0 = blockIdx.x * CH;
    int o = threadIdx.x;  // 128
    int nend = min(n0 + CH, N_NODES);
    if (n0 >= N_NODES) return;
    int curg = batch[n0];
    float run = 0.f;
    for (int n = n0; n < nend; ++n) {
        int g = batch[n];
        if (g != curg) {
            atomicAdd(&acc[(size_t)curg * HID + o], run);
            run = 0.f;
            curg = g;
        }
        run += h[(size_t)n * HID + o];
    }
    atomicAdd(&acc[(size_t)curg * HID + o], run);
}

__global__ void k_final(const float* __restrict__ acc, const float* __restrict__ cntG,
                        float* __restrict__ out) {
    int idx = blockIdx.x * blockDim.x + threadIdx.x;
    if (idx >= N_GRAPHS * HID) return;
    int g = idx >> 7;
    out[idx] = acc[idx] / fmaxf(cntG[g], 1.0f);
}

extern "C" void kernel_launch(void* const* d_in, const int* in_sizes, int n_in,
                              void* d_out, int out_size, void* d_ws, size_t ws_size,
                              hipStream_t stream) {
    const int*   x         = (const int*)d_in[0];
    const int*   edge_index= (const int*)d_in[1];
    const int*   etype     = (const int*)d_in[2];
    const int*   batch     = (const int*)d_in[3];
    const float* node_emb  = (const float*)d_in[4];
    const float* comp1     = (const float*)d_in[5];
    const float* basis1    = (const float*)d_in[6];
    const float* root1     = (const float*)d_in[7];
    const float* bias1     = (const float*)d_in[8];
    const float* comp2     = (const float*)d_in[9];
    const float* basis2    = (const float*)d_in[10];
    const float* root2     = (const float*)d_in[11];
    const float* bias2     = (const float*)d_in[12];
    float* out = (float*)d_out;

    const int* src = edge_index;
    const int* dst = edge_index + N_EDGES;

    float* ws = (float*)d_ws;
    unsigned short* Wf1 = (unsigned short*)(ws + OFF_WF1);
    unsigned short* Wf2 = (unsigned short*)(ws + OFF_WF2);
    float* cnt_t = ws + OFF_CNT;                     // becomes invcnt_t in place
    float* h1   = ws + OFF_H1;
    float* h2   = ws + OFF_H2;
    unsigned short* hb1 = (unsigned short*)(ws + OFF_HB1);
    unsigned short* hb2 = (unsigned short*)(ws + OFF_HB2);
    float* cntG = ws + OFF_CNTG;
    float* pool = ws + OFF_POOL;
    int*   ps_src = (int*)(ws + OFF_PSRC);
    int*   ps_os  = (int*)(ws + OFF_POS);
    int*   ps_dst = (int*)(ws + OFF_PDST);
    int*   hist_cr = (int*)(ws + OFF_HCR);
    int*   cur_cr  = (int*)(ws + OFF_CCR);
    int*   po_cr   = (int*)(ws + OFF_POCR);
    int*   hist_d  = (int*)(ws + OFF_HD);
    int*   cur_d   = (int*)(ws + OFF_CD);
    int*   po_d    = (int*)(ws + OFF_POD);
    unsigned short* rf1 = (unsigned short*)(ws + OFF_RF1);
    unsigned short* rf2 = (unsigned short*)(ws + OFF_RF2);
    unsigned int* pm = (unsigned int*)(ws + OFF_PM);

    // ---- choose chunk count from workspace size (deterministic) ----
    size_t ws_floats = ws_size / sizeof(float);
    int nch = 4;
    if (ws_floats >= OFF_PM + ((size_t)N_EDGES / 1 + 12504) * 64) nch = 1;
    else if (ws_floats >= OFF_PM + ((size_t)N_EDGES / 2 + 12504) * 64) nch = 2;
    int chn = N_NODES / nch;
    int nkeyc = nch * N_REL;
    int capr = N_EDGES / nch + 12504;
    int gridm = (capr + 255) / 256 + N_REL;          // k_msg grid (early-exit covers)

    hipMemsetAsync(cnt_t, 0, (size_t)N_NODES * N_REL * sizeof(float), stream);
    hipMemsetAsync(cntG, 0, (size_t)(N_GRAPHS + N_GRAPHS * HID) * sizeof(float), stream);
    hipMemsetAsync(hist_cr, 0, 2 * NKEYC_MAX * sizeof(int), stream);  // hist_cr + cur_cr
    hipMemsetAsync(cur_d, 0, N_NODES * sizeof(int), stream);

    // ---- prep (serves both layers) ----
    k_count<<<(N_EDGES + 255) / 256, 256, 0, stream>>>(dst, etype, cnt_t);
    k_deg_inv<<<(N_NODES + 255) / 256, 256, 0, stream>>>(cnt_t, hist_d);
    k_scan_d<<<1, 256, 0, stream>>>(hist_d, po_d);
    k_hist_cr<<<(N_EDGES + 255) / 256, 256, 0, stream>>>(dst, etype, hist_cr, chn, nkeyc);
    k_scan_cr<<<1, 64, 0, stream>>>(hist_cr, po_cr, nkeyc);
    k_fill<<<2048, 256, 0, stream>>>(ps_src, ps_os, ps_dst, capr - 1);
    k_scatter_s<<<(N_EDGES + SP_EPB - 1) / SP_EPB, 256, 0, stream>>>(
        src, dst, etype, po_cr, cur_cr, po_d, cur_d, ps_src, ps_os, ps_dst, chn, nkeyc);

    // fragment-ordered bf16 weights + root matrices
    k_Wfrag<EMB, 2><<<(N_REL * EMB * HID + 255) / 256, 256, 0, stream>>>(comp1, basis1, Wf1);
    k_Wfrag<HID, 4><<<(N_REL * HID * HID + 255) / 256, 256, 0, stream>>>(comp2, basis2, Wf2);
    k_rootfrag<EMB, 2><<<(EMB * HID + 255) / 256, 256, 0, stream>>>(root1, rf1);
    k_rootfrag<HID, 4><<<(HID * HID + 255) / 256, 256, 0, stream>>>(root2, rf2);

    // ---- layer 1 ----
    k_cvt_emb<<<(N_NODES * (EMB / 4) + 255) / 256, 256, 0, stream>>>(node_emb, x, hb1);
    k_rootgemm<EMB, 2><<<(N_NODES + 63) / 64, 256, 0, stream>>>(hb1, rf1, bias1, h1);
    for (int c = 0; c < nch; ++c) {
        k_msg<EMB, 2><<<gridm, 256, 0, stream>>>(hb1, ps_src, ps_os, ps_dst, cnt_t,
                                                 po_cr + c * N_REL, Wf1, pm);
        k_reduce<true><<<chn / 4, 256, 0, stream>>>(pm, po_d, c * chn, chn, h1, hb2);
    }

    // ---- layer 2 ----
    k_rootgemm<HID, 4><<<(N_NODES + 63) / 64, 256, 0, stream>>>(hb2, rf2, bias2, h2);
    for (int c = 0; c < nch; ++c) {
        k_msg<HID, 4><<<gridm, 256, 0, stream>>>(hb2, ps_src, ps_os, ps_dst, cnt_t,
                                                 po_cr + c * N_REL, Wf2, pm);
        k_reduce<false><<<chn / 4, 256, 0, stream>>>(pm, po_d, c * chn, chn, h2, nullptr);
    }

    // ---- global mean pool ----
    k_gcount2<<<1, 64, 0, stream>>>(batch, cntG);
    k_pool<<<(N_NODES + 63) / 64, HID, 0, stream>>>(h2, batch, pool);
    k_final<<<(N_GRAPHS * HID + 255) / 256, 256, 0, stream>>>(pool, cntG, out);
}

// Round 16
// 1016.095 us; speedup vs baseline: 1.5356x; 1.5356x over previous
//
#include <hip/hip_runtime.h>

// RGCN 2-layer graph encoder — R16: R13 hot path (proven 1021us) + prep fusion.
//  * k_count_hist: single edge pass does cnt_t atomics + (chunk,rel) LDS hist
//  * k_fillpads: init only pad slots (R11-proven) instead of 15MB full fill
//  * brel block->rel byte table (R11-proven) replaces k_msg's serial scan
//  Hot kernels (k_msg/k_reduce/k_rootgemm) byte-identical to R13.

#define N_NODES 50000
#define N_EDGES 1200000
#define N_REL   40
#define N_BASES 30
#define EMB     64
#define HID     128
#define N_GRAPHS 64

#define NKEYC_MAX 160                                   // up to 4 chunks * 40 rels
#define PERM_CAP  ((size_t)N_EDGES + (size_t)NKEYC_MAX * 256)
#define SP_EPB    1024

typedef float f32x4  __attribute__((ext_vector_type(4)));
typedef short bf16x8 __attribute__((ext_vector_type(8)));

__device__ __forceinline__ unsigned short f2bf(float x) {
    unsigned int u = __float_as_uint(x);
    u = (u + 0x7FFFu + ((u >> 16) & 1u)) >> 16;   // RNE
    return (unsigned short)u;
}
__device__ __forceinline__ float bflo(unsigned int u) { return __uint_as_float(u << 16); }
__device__ __forceinline__ float bfhi(unsigned int u) { return __uint_as_float(u & 0xffff0000u); }

// ---------------- workspace layout (float units) ----------------
#define OFF_WF1   ((size_t)0)                    // 163,840
#define OFF_WF2   ((size_t)163840)               // 327,680
#define OFF_CNT   ((size_t)491520)               // 2,000,000 (cnt_t[r][n] -> inv)
#define OFF_H1    ((size_t)2491520)              // 6,400,000
#define OFF_H2    ((size_t)8891520)              // 6,400,000
#define OFF_HB1   ((size_t)15291520)             // 1,600,000
#define OFF_HB2   ((size_t)16891520)             // 3,200,000
#define OFF_CNTG  ((size_t)20091520)             // 64
#define OFF_POOL  ((size_t)20091584)             // 8,192
#define OFF_PSRC  ((size_t)20099776)             // 1,240,960
#define OFF_POS   ((size_t)21340736)             // 1,240,960
#define OFF_PDST  ((size_t)22581696)             // 1,240,960
#define OFF_HCR   ((size_t)23822656)             // 160
#define OFF_CCR   ((size_t)23822816)             // 160
#define OFF_POCR  ((size_t)23822976)             // 192 (161 used)
#define OFF_HD    ((size_t)23823168)             // 50,000
#define OFF_CD    ((size_t)23873168)             // 50,000
#define OFF_POD   ((size_t)23923168)             // 50,016
#define OFF_RF1   ((size_t)23973184)             // 4,096
#define OFF_RF2   ((size_t)23977280)             // 8,192
#define OFF_BREL  ((size_t)23985472)             // 2,048 floats (8192 bytes)
#define OFF_PM    ((size_t)23987520)             // capr(nch)*64 u32

// ---- W fragment generator (16x16x32 layout):
// Wf[r][((ct*KT+kt)*64+lane)*8+j] = W_r[kt*32+(lane>>4)*8+j][ct*16+(lane&15)]
template <int IN, int KT>
__global__ void k_Wfrag(const float* __restrict__ comp, const float* __restrict__ basis,
                        unsigned short* __restrict__ Wf) {
    const int FR = IN * HID;
    int idx = blockIdx.x * blockDim.x + threadIdx.x;
    if (idx >= N_REL * FR) return;
    int r = idx / FR, F = idx - r * FR;
    int j = F & 7, lane = (F >> 3) & 63, tt = F >> 9;
    int kt = tt % KT, ct = tt / KT;
    int k = kt * 32 + (lane >> 4) * 8 + j;
    int c = ct * 16 + (lane & 15);
    float s = 0.f;
#pragma unroll
    for (int b = 0; b < N_BASES; ++b)
        s += comp[r * N_BASES + b] * basis[((size_t)b * IN + k) * HID + c];
    Wf[idx] = f2bf(s);
}

template <int IN, int KT>
__global__ void k_rootfrag(const float* __restrict__ root, unsigned short* __restrict__ rf) {
    int idx = blockIdx.x * blockDim.x + threadIdx.x;
    if (idx >= IN * HID) return;
    int j = idx & 7, lane = (idx >> 3) & 63, tt = idx >> 9;
    int kt = tt % KT, ct = tt / KT;
    int k = kt * 32 + (lane >> 4) * 8 + j;
    int c = ct * 16 + (lane & 15);
    rf[idx] = f2bf(root[k * HID + c]);
}

// fused: transposed (dst,rel) count atomics + (chunk,rel) LDS histogram
__global__ void k_count_hist(const int* __restrict__ dst, const int* __restrict__ etype,
                             float* __restrict__ cnt_t, int* __restrict__ hist,
                             int chn, int nkeyc) {
    __shared__ int lh[NKEYC_MAX];
    int t = threadIdx.x;
    if (t < nkeyc) lh[t] = 0;
    __syncthreads();
    int e = blockIdx.x * blockDim.x + t;
    if (e < N_EDGES) {
        int d = dst[e], r = etype[e];
        atomicAdd(&cnt_t[(size_t)r * N_NODES + d], 1.0f);
        atomicAdd(&lh[(d / chn) * N_REL + r], 1);
    }
    __syncthreads();
    if (t < nkeyc && lh[t]) atomicAdd(&hist[t], lh[t]);
}

// degree per node + IN-PLACE cnt_t -> 1/max(cnt,1)
__global__ void k_deg_inv(float* __restrict__ cnt_t, int* __restrict__ hist) {
    int n = blockIdx.x * blockDim.x + threadIdx.x;
    if (n >= N_NODES) return;
    float s = 0.f;
#pragma unroll 8
    for (int r = 0; r < N_REL; ++r) {
        float c = cnt_t[(size_t)r * N_NODES + n];
        s += c;
        cnt_t[(size_t)r * N_NODES + n] = 1.0f / fmaxf(c, 1.0f);
    }
    hist[n] = (int)(s + 0.5f);
}

// exclusive scan over N_NODES entries, po_d[N]=E
__global__ void k_scan_d(const int* __restrict__ hist, int* __restrict__ po) {
    __shared__ int csum[256];
    int t = threadIdx.x;
    const int CH = (N_NODES + 255) / 256;
    int k0 = t * CH, k1 = min(k0 + CH, N_NODES);
    int s = 0;
    for (int k = k0; k < k1; ++k) s += hist[k];
    csum[t] = s;
    __syncthreads();
    if (t == 0) {
        int acc = 0;
        for (int i = 0; i < 256; ++i) { int v = csum[i]; csum[i] = acc; acc += v; }
        po[N_NODES] = acc;
    }
    __syncthreads();
    int base = csum[t];
    for (int k = k0; k < k1; ++k) { po[k] = base; base += hist[k]; }
}

// scan nkeyc buckets, each padded to a multiple of 256
__global__ void k_scan_cr(const int* __restrict__ hist, int* __restrict__ po, int nkeyc) {
    if (threadIdx.x == 0) {
        int acc = 0;
        for (int k = 0; k < nkeyc; ++k) {
            po[k] = acc;
            acc += ((hist[k] + 255) >> 8) << 8;
        }
        po[nkeyc] = acc;
    }
}

// block(256-slot) -> rel byte table (bucket starts are 256-aligned)
__global__ void k_brel(const int* __restrict__ po, unsigned char* __restrict__ brel,
                       int nkeyc) {
    int k = blockIdx.x * blockDim.x + threadIdx.x;
    if (k >= nkeyc) return;
    unsigned char r = (unsigned char)(k % N_REL);
    for (int b = po[k] >> 8; b < (po[k + 1] >> 8); ++b) brel[b] = r;
}

// pad-slot init only (replaces 15MB full-stream fill)
__global__ void k_fillpads(const int* __restrict__ hist, const int* __restrict__ po,
                           int* __restrict__ ps_src, int* __restrict__ ps_os,
                           int* __restrict__ ps_dst, int dumprow, int nkeyc) {
    int k = blockIdx.x;  // nkeyc
    if (k >= nkeyc) return;
    int start = po[k] + hist[k], end = po[k + 1];
    for (int s = start + threadIdx.x; s < end; s += blockDim.x) {
        ps_src[s] = 0;
        ps_os[s] = dumprow;
        ps_dst[s] = 0;
    }
}

// block-aggregated scatter into (chunk,rel)-major slots + dst-major oslot
__global__ void k_scatter_s(const int* __restrict__ src, const int* __restrict__ dst,
                            const int* __restrict__ etype,
                            const int* __restrict__ po_cr, int* __restrict__ cur_cr,
                            const int* __restrict__ po_d, int* __restrict__ cur_d,
                            int* __restrict__ ps_src, int* __restrict__ ps_os,
                            int* __restrict__ ps_dst, int chn, int nkeyc) {
    __shared__ int lh[NKEYC_MAX], sbase[NKEYC_MAX];
    int t = threadIdx.x;  // 256
    if (t < nkeyc) lh[t] = 0;
    __syncthreads();
    int e0 = blockIdx.x * SP_EPB;
    int e_[4], key_[4];
#pragma unroll
    for (int i = 0; i < 4; ++i) {
        int e = e0 + t + i * 256;
        e_[i] = e;
        if (e < N_EDGES) {
            key_[i] = (dst[e] / chn) * N_REL + etype[e];
            atomicAdd(&lh[key_[i]], 1);
        }
    }
    __syncthreads();
    if (t < nkeyc) { if (lh[t]) sbase[t] = atomicAdd(&cur_cr[t], lh[t]); lh[t] = 0; }
    __syncthreads();
#pragma unroll
    for (int i = 0; i < 4; ++i) {
        if (e_[i] < N_EDGES) {
            int e = e_[i], key = key_[i];
            int d = dst[e];
            int p = atomicAdd(&lh[key], 1);
            int slot = po_cr[key] + sbase[key] + p;
            int os_g = po_d[d] + atomicAdd(&cur_d[d], 1);
            int os_l = os_g - po_d[(d / chn) * chn];   // chunk-local pm row
            ps_src[slot] = src[e];
            ps_os[slot] = os_l;
            ps_dst[slot] = d;
        }
    }
}

// ---- MFMA root GEMM: h[n] = bias + hb[n] @ root ----
template <int IN, int KT>
__global__ __launch_bounds__(256, 4)
void k_rootgemm(const unsigned short* __restrict__ hb_in,
                const unsigned short* __restrict__ rf,
                const float* __restrict__ bias, float* __restrict__ h) {
    __shared__ unsigned short Wl[8 * KT * 64 * 8];
    {
        const f32x4* Wg = (const f32x4*)rf;
        f32x4* Wd = (f32x4*)Wl;
        for (int kk = threadIdx.x; kk < 8 * KT * 64; kk += 256) Wd[kk] = Wg[kk];
    }
    __syncthreads();

    int l = threadIdx.x & 63, wv = threadIdx.x >> 6;
    int lrow = l & 15, lk = l >> 4;
    int nbase = blockIdx.x * 64 + wv * 16;

    int nrow = min(nbase + lrow, N_NODES - 1);
    bf16x8 a[KT];
    const unsigned short* hrow = hb_in + (size_t)nrow * IN + lk * 8;
#pragma unroll
    for (int kt = 0; kt < KT; ++kt)
        a[kt] = *(const bf16x8*)(hrow + kt * 32);

    f32x4 acc[8];
#pragma unroll
    for (int ct = 0; ct < 8; ++ct) acc[ct] = (f32x4){0.f, 0.f, 0.f, 0.f};
#pragma unroll
    for (int ct = 0; ct < 8; ++ct) {
#pragma unroll
        for (int kt = 0; kt < KT; ++kt) {
            bf16x8 bb = *(const bf16x8*)(Wl + ((ct * KT + kt) * 64 + l) * 8);
            acc[ct] = __builtin_amdgcn_mfma_f32_16x16x32_bf16(a[kt], bb, acc[ct], 0, 0, 0);
        }
    }
#pragma unroll
    for (int q = 0; q < 4; ++q) {
        int n = nbase + lk * 4 + q;
        if (n < N_NODES) {
#pragma unroll
            for (int ct = 0; ct < 8; ++ct)
                h[(size_t)n * HID + ct * 16 + lrow] = acc[ct][q] + bias[ct * 16 + lrow];
        }
    }
}

// ---- Phase A: rel-major MFMA message kernel (R13 structure + brel) ----
template <int IN, int KT>
__global__ __launch_bounds__(256, 4)
void k_msg(const unsigned short* __restrict__ hb_in, const int* __restrict__ ps_src,
           const int* __restrict__ ps_os, const int* __restrict__ ps_dst,
           const float* __restrict__ invc_t,
           const int* __restrict__ po_c,    // 41 entries for this chunk
           const unsigned char* __restrict__ brel,
           const unsigned short* __restrict__ Wf, unsigned int* __restrict__ pm) {
    __shared__ unsigned short Wl[8 * KT * 64 * 8];
    int slot0 = po_c[0] + blockIdx.x * 256;
    if (slot0 >= po_c[N_REL]) return;
    int r = brel[slot0 >> 8];

    {   // stage W_r fragments -> LDS
        const f32x4* Wg = (const f32x4*)(Wf + (size_t)r * (8 * KT * 64 * 8));
        f32x4* Wd = (f32x4*)Wl;
        for (int kk = threadIdx.x; kk < 8 * KT * 64; kk += 256) Wd[kk] = Wg[kk];
    }
    __syncthreads();

    int l = threadIdx.x & 63, wv = threadIdx.x >> 6;
    int lrow = l & 15, lk = l >> 4;
    const float* invr = invc_t + (size_t)r * N_NODES;

    for (int t = wv; t < 16; t += 4) {
        int slot = slot0 + t * 16 + lrow;
        int sv = ps_src[slot];
        int os = ps_os[slot];
        int d  = ps_dst[slot];
        float inv = invr[d];

        bf16x8 a[KT];
        const unsigned short* hrow = hb_in + (size_t)sv * IN + lk * 8;
#pragma unroll
        for (int kt = 0; kt < KT; ++kt)
            a[kt] = *(const bf16x8*)(hrow + kt * 32);

        f32x4 acc[8];
#pragma unroll
        for (int ct = 0; ct < 8; ++ct) acc[ct] = (f32x4){0.f, 0.f, 0.f, 0.f};
#pragma unroll
        for (int ct = 0; ct < 8; ++ct) {
#pragma unroll
            for (int kt = 0; kt < KT; ++kt) {
                bf16x8 bb = *(const bf16x8*)(Wl + ((ct * KT + kt) * 64 + l) * 8);
                acc[ct] = __builtin_amdgcn_mfma_f32_16x16x32_bf16(a[kt], bb, acc[ct], 0, 0, 0);
            }
        }
        // scaled bf16-pack NONTEMPORAL store (pm written once, read once)
#pragma unroll
        for (int q = 0; q < 4; ++q) {
            int row = lk * 4 + q;
            int osq   = __shfl(os, row);
            float ivq = __shfl(inv, row);
            unsigned int* dp = pm + (size_t)osq * 64 + lrow;
#pragma unroll
            for (int cp = 0; cp < 4; ++cp) {
                unsigned int u = (unsigned int)f2bf(acc[2 * cp][q] * ivq)
                               | ((unsigned int)f2bf(acc[2 * cp + 1][q] * ivq) << 16);
                __builtin_nontemporal_store(u, dp + cp * 16);
            }
        }
    }
}

// ---- Phase B: dst-major streaming reduce (nontemporal pm loads) ----
template <bool WRITE_HB>
__global__ __launch_bounds__(256, 8)
void k_reduce(const unsigned int* __restrict__ pm, const int* __restrict__ po_d,
              int n0chunk, int chn, float* __restrict__ h,
              unsigned short* __restrict__ hb_out) {
    int wv = threadIdx.x >> 6, p = threadIdx.x & 63;
    int n = n0chunk + blockIdx.x * 4 + wv;
    if (n >= n0chunk + chn) return;
    int pmbase = po_d[n0chunk];
    int b0 = po_d[n] - pmbase;
    int cn = po_d[n + 1] - pmbase - b0;
    float lo = 0.f, hi = 0.f;
    const unsigned int* rp = pm + (size_t)b0 * 64 + p;
    int k = 0;
    for (; k + 4 <= cn; k += 4) {
        unsigned int u0 = __builtin_nontemporal_load(rp);
        unsigned int u1 = __builtin_nontemporal_load(rp + 64);
        unsigned int u2 = __builtin_nontemporal_load(rp + 128);
        unsigned int u3 = __builtin_nontemporal_load(rp + 192);
        rp += 256;
        lo += bflo(u0) + bflo(u1) + bflo(u2) + bflo(u3);
        hi += bfhi(u0) + bfhi(u1) + bfhi(u2) + bfhi(u3);
    }
    for (; k < cn; ++k) {
        unsigned int u = __builtin_nontemporal_load(rp);
        rp += 64;
        lo += bflo(u); hi += bfhi(u);
    }
    int cA = (p & 15) + 32 * (p >> 4);
    float* hp = h + (size_t)n * HID;
    float vA = fmaxf(hp[cA] + lo, 0.f);
    float vB = fmaxf(hp[cA + 16] + hi, 0.f);
    hp[cA] = vA;
    hp[cA + 16] = vB;
    if (WRITE_HB) {
        hb_out[(size_t)n * HID + cA] = f2bf(vA);
        hb_out[(size_t)n * HID + cA + 16] = f2bf(vB);
    }
}

// layer-1 A source: hb1[n][:] = bf16(node_emb[x[n]][:])
__global__ void k_cvt_emb(const float* __restrict__ emb, const int* __restrict__ x,
                          unsigned short* __restrict__ hb) {
    int idx = blockIdx.x * blockDim.x + threadIdx.x;
    if (idx >= N_NODES * (EMB / 4)) return;
    int n = idx / (EMB / 4), c4 = idx % (EMB / 4);
    int row = x[n];
    float4 v = *(const float4*)(emb + (size_t)row * EMB + c4 * 4);
    ushort4 o = {f2bf(v.x), f2bf(v.y), f2bf(v.z), f2bf(v.w)};
    *(ushort4*)(hb + (size_t)n * EMB + c4 * 4) = o;
}

__global__ void k_gcount2(const int* __restrict__ batch, float* __restrict__ cntG) {
    int g = threadIdx.x;
    if (g >= N_GRAPHS) return;
    int lo = 0, hi = N_NODES;
    while (lo < hi) { int m = (lo + hi) >> 1; if (batch[m] < g) lo = m + 1; else hi = m; }
    int lb0 = lo;
    lo = 0; hi = N_NODES;
    while (lo < hi) { int m = (lo + hi) >> 1; if (batch[m] < g + 1) lo = m + 1; else hi = m; }
    cntG[g] = (float)(lo - lb0);
}

__global__ void k_pool(const float* __restrict__ h, const int* __restrict__ batch,
                       float* __restrict__ acc) {
    const int CH = 64;
    int n0 = blockIdx.x * CH;
    int o = threadIdx.x;  // 128
    int nend = min(n0 + CH, N_NODES);
    if (n0 >= N_NODES) return;
    int curg = batch[n0];
    float run = 0.f;
    for (int n = n0; n < nend; ++n) {
        int g = batch[n];
        if (g != curg) {
            atomicAdd(&acc[(size_t)curg * HID + o], run);
            run = 0.f;
            curg = g;
        }
        run += h[(size_t)n * HID + o];
    }
    atomicAdd(&acc[(size_t)curg * HID + o], run);
}

__global__ void k_final(const float* __restrict__ acc, const float* __restrict__ cntG,
                        float* __restrict__ out) {
    int idx = blockIdx.x * blockDim.x + threadIdx.x;
    if (idx >= N_GRAPHS * HID) return;
    int g = idx >> 7;
    out[idx] = acc[idx] / fmaxf(cntG[g], 1.0f);
}

extern "C" void kernel_launch(void* const* d_in, const int* in_sizes, int n_in,
                              void* d_out, int out_size, void* d_ws, size_t ws_size,
                              hipStream_t stream) {
    const int*   x         = (const int*)d_in[0];
    const int*   edge_index= (const int*)d_in[1];
    const int*   etype     = (const int*)d_in[2];
    const int*   batch     = (const int*)d_in[3];
    const float* node_emb  = (const float*)d_in[4];
    const float* comp1     = (const float*)d_in[5];
    const float* basis1    = (const float*)d_in[6];
    const float* root1     = (const float*)d_in[7];
    const float* bias1     = (const float*)d_in[8];
    const float* comp2     = (const float*)d_in[9];
    const float* basis2    = (const float*)d_in[10];
    const float* root2     = (const float*)d_in[11];
    const float* bias2     = (const float*)d_in[12];
    float* out = (float*)d_out;

    const int* src = edge_index;
    const int* dst = edge_index + N_EDGES;

    float* ws = (float*)d_ws;
    unsigned short* Wf1 = (unsigned short*)(ws + OFF_WF1);
    unsigned short* Wf2 = (unsigned short*)(ws + OFF_WF2);
    float* cnt_t = ws + OFF_CNT;                     // becomes invcnt_t in place
    float* h1   = ws + OFF_H1;
    float* h2   = ws + OFF_H2;
    unsigned short* hb1 = (unsigned short*)(ws + OFF_HB1);
    unsigned short* hb2 = (unsigned short*)(ws + OFF_HB2);
    float* cntG = ws + OFF_CNTG;
    float* pool = ws + OFF_POOL;
    int*   ps_src = (int*)(ws + OFF_PSRC);
    int*   ps_os  = (int*)(ws + OFF_POS);
    int*   ps_dst = (int*)(ws + OFF_PDST);
    int*   hist_cr = (int*)(ws + OFF_HCR);
    int*   cur_cr  = (int*)(ws + OFF_CCR);
    int*   po_cr   = (int*)(ws + OFF_POCR);
    int*   hist_d  = (int*)(ws + OFF_HD);
    int*   cur_d   = (int*)(ws + OFF_CD);
    int*   po_d    = (int*)(ws + OFF_POD);
    unsigned short* rf1 = (unsigned short*)(ws + OFF_RF1);
    unsigned short* rf2 = (unsigned short*)(ws + OFF_RF2);
    unsigned char* brel = (unsigned char*)(ws + OFF_BREL);
    unsigned int* pm = (unsigned int*)(ws + OFF_PM);

    // ---- choose chunk count from workspace size (deterministic) ----
    size_t ws_floats = ws_size / sizeof(float);
    int nch = 4;
    if (ws_floats >= OFF_PM + ((size_t)N_EDGES / 1 + 12504) * 64) nch = 1;
    else if (ws_floats >= OFF_PM + ((size_t)N_EDGES / 2 + 12504) * 64) nch = 2;
    int chn = N_NODES / nch;
    int nkeyc = nch * N_REL;
    int capr = N_EDGES / nch + 12504;
    int gridm = (capr + 255) / 256 + N_REL;          // k_msg grid (early-exit covers)

    hipMemsetAsync(cnt_t, 0, (size_t)N_NODES * N_REL * sizeof(float), stream);
    hipMemsetAsync(cntG, 0, (size_t)(N_GRAPHS + N_GRAPHS * HID) * sizeof(float), stream);
    hipMemsetAsync(hist_cr, 0, 2 * NKEYC_MAX * sizeof(int), stream);  // hist_cr + cur_cr
    hipMemsetAsync(cur_d, 0, N_NODES * sizeof(int), stream);

    // ---- prep (serves both layers) ----
    k_count_hist<<<(N_EDGES + 255) / 256, 256, 0, stream>>>(dst, etype, cnt_t, hist_cr,
                                                            chn, nkeyc);
    k_deg_inv<<<(N_NODES + 255) / 256, 256, 0, stream>>>(cnt_t, hist_d);
    k_scan_d<<<1, 256, 0, stream>>>(hist_d, po_d);
    k_scan_cr<<<1, 64, 0, stream>>>(hist_cr, po_cr, nkeyc);
    k_brel<<<1, 256, 0, stream>>>(po_cr, brel, nkeyc);
    k_fillpads<<<nkeyc, 256, 0, stream>>>(hist_cr, po_cr, ps_src, ps_os, ps_dst,
                                          capr - 1, nkeyc);
    k_scatter_s<<<(N_EDGES + SP_EPB - 1) / SP_EPB, 256, 0, stream>>>(
        src, dst, etype, po_cr, cur_cr, po_d, cur_d, ps_src, ps_os, ps_dst, chn, nkeyc);

    // fragment-ordered bf16 weights + root matrices
    k_Wfrag<EMB, 2><<<(N_REL * EMB * HID + 255) / 256, 256, 0, stream>>>(comp1, basis1, Wf1);
    k_Wfrag<HID, 4><<<(N_REL * HID * HID + 255) / 256, 256, 0, stream>>>(comp2, basis2, Wf2);
    k_rootfrag<EMB, 2><<<(EMB * HID + 255) / 256, 256, 0, stream>>>(root1, rf1);
    k_rootfrag<HID, 4><<<(HID * HID + 255) / 256, 256, 0, stream>>>(root2, rf2);

    // ---- layer 1 ----
    k_cvt_emb<<<(N_NODES * (EMB / 4) + 255) / 256, 256, 0, stream>>>(node_emb, x, hb1);
    k_rootgemm<EMB, 2><<<(N_NODES + 63) / 64, 256, 0, stream>>>(hb1, rf1, bias1, h1);
    for (int c = 0; c < nch; ++c) {
        k_msg<EMB, 2><<<gridm, 256, 0, stream>>>(hb1, ps_src, ps_os, ps_dst, cnt_t,
                                                 po_cr + c * N_REL, brel, Wf1, pm);
        k_reduce<true><<<chn / 4, 256, 0, stream>>>(pm, po_d, c * chn, chn, h1, hb2);
    }

    // ---- layer 2 ----
    k_rootgemm<HID, 4><<<(N_NODES + 63) / 64, 256, 0, stream>>>(hb2, rf2, bias2, h2);
    for (int c = 0; c < nch; ++c) {
        k_msg<HID, 4><<<gridm, 256, 0, stream>>>(hb2, ps_src, ps_os, ps_dst, cnt_t,
                                                 po_cr + c * N_REL, brel, Wf2, pm);
        k_reduce<false><<<chn / 4, 256, 0, stream>>>(pm, po_d, c * chn, chn, h2, nullptr);
    }

    // ---- global mean pool ----
    k_gcount2<<<1, 64, 0, stream>>>(batch, cntG);
    k_pool<<<(N_NODES + 63) / 64, HID, 0, stream>>>(h2, batch, pool);
    k_final<<<(N_GRAPHS * HID + 255) / 256, 256, 0, stream>>>(pool, cntG, out);
}